// Round 1
// baseline (20909.775 us; speedup 1.0000x reference)
//
#include <hip/hip_runtime.h>
#include <math.h>

#define NB 32      // batch
#define NS 64      // src len
#define NT 64      // trg len
#define NE 512     // embed
#define NH 512     // enc hidden
#define NHD 1024   // dec hidden (2H)
#define NV 32000   // vocab
#define NR 2016    // decoder rows = (NT-1)*NB
#define NCT 500    // col tiles in gemmlse = NV/64

__device__ __forceinline__ float sigmf(float x) { return 1.f / (1.f + expf(-x)); }

// ---------- embedding gathers ----------
__global__ void gather_src_kernel(const int* tok, const float* emb, float* out) {
  int idx = blockIdx.x * blockDim.x + threadIdx.x;  // over 2048*128 float4
  int m = idx >> 7;
  int e4 = idx & 127;
  if (m >= NB * NS) return;
  const float4* src = (const float4*)(emb + (size_t)tok[m] * NE);
  ((float4*)(out + (size_t)m * NE))[e4] = src[e4];
}

__global__ void gather_trg_kernel(const int* tok, const float* emb, float* out) {
  int idx = blockIdx.x * blockDim.x + threadIdx.x;  // over 2016*128 float4
  int m = idx >> 7;
  int e4 = idx & 127;
  if (m >= NR) return;
  int t = m >> 5, b = m & 31;  // row m = t*32 + b
  int token = tok[b * NT + t];
  const float4* src = (const float4*)(emb + (size_t)token * NE);
  ((float4*)(out + (size_t)m * NE))[e4] = src[e4];
}

__global__ void zero_kernel(float* p, int n) {
  int i = blockIdx.x * blockDim.x + threadIdx.x;
  if (i < n) p[i] = 0.f;
}

// ---------- generic fp32 GEMM: C[m,n] = sum_k A[m,k]*B[n,k] + b0[n] + b1[n] ----------
// BM=BN=64, BK=16, 256 threads, 4x4 per thread. N must be divisible by 64.
__global__ __launch_bounds__(256) void gemm_abT_kernel(
    const float* __restrict__ A, const float* __restrict__ Bm,
    const float* __restrict__ b0, const float* __restrict__ b1,
    float* __restrict__ C, int M, int N, int K) {
  __shared__ float As[16][68];
  __shared__ float Bs[16][68];
  int tid = threadIdx.x;
  int tm = tid >> 4, tn = tid & 15;
  int row0 = blockIdx.y * 64;
  int col0 = blockIdx.x * 64;
  float acc[4][4] = {};
  for (int k0 = 0; k0 < K; k0 += 16) {
#pragma unroll
    for (int i = 0; i < 4; i++) {
      int r = tm + i * 16;
      int gm = row0 + r;
      As[tn][r] = (gm < M) ? A[(size_t)gm * K + k0 + tn] : 0.f;
      Bs[tn][r] = Bm[(size_t)(col0 + r) * K + k0 + tn];
    }
    __syncthreads();
#pragma unroll
    for (int k = 0; k < 16; k++) {
      float a4[4], b4[4];
#pragma unroll
      for (int i = 0; i < 4; i++) a4[i] = As[k][tm * 4 + i];
#pragma unroll
      for (int j = 0; j < 4; j++) b4[j] = Bs[k][tn * 4 + j];
#pragma unroll
      for (int i = 0; i < 4; i++)
#pragma unroll
        for (int j = 0; j < 4; j++) acc[i][j] += a4[i] * b4[j];
    }
    __syncthreads();
  }
#pragma unroll
  for (int i = 0; i < 4; i++) {
    int gm = row0 + tm * 4 + i;
    if (gm >= M) continue;
#pragma unroll
    for (int j = 0; j < 4; j++) {
      int gn = col0 + tn * 4 + j;
      C[(size_t)gm * N + gn] = acc[i][j] + b0[gn] + b1[gn];
    }
  }
}

// ---------- encoder step: both LSTMs fused, thread per (lstm, b, j) ----------
__global__ __launch_bounds__(256) void enc_step_kernel(
    const float* __restrict__ Aef, const float* __restrict__ Aer,
    const float* __restrict__ Wehh, const float* __restrict__ Wrhh,
    const float* __restrict__ hpf, const float* __restrict__ cpf,
    float* __restrict__ hnf, float* __restrict__ cnf,
    const float* __restrict__ hpr, const float* __restrict__ cpr,
    float* __restrict__ hnr, float* __restrict__ cnr,
    float* __restrict__ ss, int t) {
  int idx = blockIdx.x * 256 + threadIdx.x;  // 0 .. 2*32*512
  int lstm = idx >> 14;
  int rem = idx & 16383;
  int b = rem >> 9;
  int j = rem & 511;
  const float* A = lstm ? Aer : Aef;
  const float* W = lstm ? Wrhh : Wehh;
  const float* hp = (lstm ? hpr : hpf) + b * NH;
  const float* cp = lstm ? cpr : cpf;
  float* hn = lstm ? hnr : hnf;
  float* cn = lstm ? cnr : cnf;
  size_t arow = ((size_t)b * NS + t) * 2048;
  float gi = A[arow + j];
  float gf = A[arow + 512 + j];
  float gg = A[arow + 1024 + j];
  float go = A[arow + 1536 + j];
  const float4* h4 = (const float4*)hp;
  const float4* Wi4 = (const float4*)(W + (size_t)j * NH);
  const float4* Wf4 = (const float4*)(W + (size_t)(512 + j) * NH);
  const float4* Wg4 = (const float4*)(W + (size_t)(1024 + j) * NH);
  const float4* Wo4 = (const float4*)(W + (size_t)(1536 + j) * NH);
  for (int k = 0; k < NH / 4; k++) {
    float4 h = h4[k];
    float4 wi = Wi4[k], wf = Wf4[k], wg = Wg4[k], wo = Wo4[k];
    gi += h.x * wi.x + h.y * wi.y + h.z * wi.z + h.w * wi.w;
    gf += h.x * wf.x + h.y * wf.y + h.z * wf.z + h.w * wf.w;
    gg += h.x * wg.x + h.y * wg.y + h.z * wg.z + h.w * wg.w;
    go += h.x * wo.x + h.y * wo.y + h.z * wo.z + h.w * wo.w;
  }
  float c = sigmf(gf) * cp[b * NH + j] + sigmf(gi) * tanhf(gg);
  float h = sigmf(go) * tanhf(c);
  hn[b * NH + j] = h;
  cn[b * NH + j] = c;
  ss[((size_t)b * NS + t) * (2 * NH) + lstm * NH + j] = h;
}

// ---------- decoder init: h0 = src_states[b, len-1, :], c0 = 0 ----------
__global__ void dec_init_kernel(const float* __restrict__ ss, const int* __restrict__ src_lens,
                                float* __restrict__ h0, float* __restrict__ c0) {
  int idx = blockIdx.x * 256 + threadIdx.x;  // 32*1024
  int b = idx >> 10, j = idx & 1023;
  int s = src_lens[b] - 1;
  h0[idx] = ss[((size_t)b * NS + s) * (2 * NH) + j];
  c0[idx] = 0.f;
}

// ---------- decoder step: thread per (b, j) ----------
__global__ __launch_bounds__(256) void dec_step_kernel(
    const float* __restrict__ Ad, const float* __restrict__ Wdhh,
    const float* __restrict__ hp, const float* __restrict__ cp,
    float* __restrict__ hn, float* __restrict__ cn,
    float* __restrict__ Yb, int t) {
  int idx = blockIdx.x * 256 + threadIdx.x;  // 32*1024
  int b = idx >> 10, j = idx & 1023;
  size_t arow = ((size_t)t * NB + b) * 4096;
  float gi = Ad[arow + j];
  float gf = Ad[arow + 1024 + j];
  float gg = Ad[arow + 2048 + j];
  float go = Ad[arow + 3072 + j];
  const float4* h4 = (const float4*)(hp + (size_t)b * NHD);
  const float4* Wi4 = (const float4*)(Wdhh + (size_t)j * NHD);
  const float4* Wf4 = (const float4*)(Wdhh + (size_t)(1024 + j) * NHD);
  const float4* Wg4 = (const float4*)(Wdhh + (size_t)(2048 + j) * NHD);
  const float4* Wo4 = (const float4*)(Wdhh + (size_t)(3072 + j) * NHD);
  for (int k = 0; k < NHD / 4; k++) {
    float4 h = h4[k];
    float4 wi = Wi4[k], wf = Wf4[k], wg = Wg4[k], wo = Wo4[k];
    gi += h.x * wi.x + h.y * wi.y + h.z * wi.z + h.w * wi.w;
    gf += h.x * wf.x + h.y * wf.y + h.z * wf.z + h.w * wf.w;
    gg += h.x * wg.x + h.y * wg.y + h.z * wg.z + h.w * wg.w;
    go += h.x * wo.x + h.y * wo.y + h.z * wo.z + h.w * wo.w;
  }
  float c = sigmf(gf) * cp[idx] + sigmf(gi) * tanhf(gg);
  float h = sigmf(go) * tanhf(c);
  hn[idx] = h;
  cn[idx] = c;
  Yb[((size_t)t * NB + b) * 2048 + j] = h;  // first half of Y row = h
}

// ---------- batched attention: block per (t,b) row, writes ctx into Y[:,1024:2048] ----------
__global__ __launch_bounds__(256) void attn_kernel(float* __restrict__ Yb,
                                                   const float* __restrict__ ss,
                                                   const int* __restrict__ src_lens) {
  __shared__ __align__(16) float hsh[NHD];
  __shared__ float sc[NS];
  __shared__ float att[NS];
  int r = blockIdx.x;
  int b = r & 31;
  int tid = threadIdx.x;
  for (int i = tid; i < NHD; i += 256) hsh[i] = Yb[(size_t)r * 2048 + i];
  __syncthreads();
  // scores: 4 threads per source position
  {
    int s = tid >> 2, q = tid & 3;
    const float4* row = (const float4*)(ss + ((size_t)b * NS + s) * (2 * NH));
    const float4* h4 = (const float4*)hsh;
    float p = 0.f;
    for (int k = q * 64; k < q * 64 + 64; k++) {
      float4 hh = h4[k];
      float4 rr = row[k];
      p += hh.x * rr.x + hh.y * rr.y + hh.z * rr.z + hh.w * rr.w;
    }
    p += __shfl_xor(p, 1);
    p += __shfl_xor(p, 2);
    if (q == 0) sc[s] = (s < src_lens[b]) ? p : -1e9f;
  }
  __syncthreads();
  if (tid < 64) {
    float v = sc[tid];
    float m = v;
#pragma unroll
    for (int off = 1; off < 64; off <<= 1) m = fmaxf(m, __shfl_xor(m, off));
    float e = expf(v - m);
    float ssum = e;
#pragma unroll
    for (int off = 1; off < 64; off <<= 1) ssum += __shfl_xor(ssum, off);
    att[tid] = e / ssum;
  }
  __syncthreads();
  float acc0 = 0, acc1 = 0, acc2 = 0, acc3 = 0;
  int d = tid * 4;
  for (int s2 = 0; s2 < NS; s2++) {
    float a = att[s2];
    const float4 rr = *(const float4*)(ss + ((size_t)b * NS + s2) * (2 * NH) + d);
    acc0 += a * rr.x;
    acc1 += a * rr.y;
    acc2 += a * rr.z;
    acc3 += a * rr.w;
  }
  float4 o = {acc0, acc1, acc2, acc3};
  *(float4*)(Yb + (size_t)r * 2048 + NHD + d) = o;
}

// ---------- fused logits GEMM + per-64-col logsumexp partials + target-logit capture ----------
// grid = (row tiles = 32, col tiles = 500). Y (2016x2048) @ W_out^T (2048x32000) + b_out.
__global__ __launch_bounds__(256) void gemmlse_kernel(
    const float* __restrict__ Y, const float* __restrict__ Wo, const float* __restrict__ bo,
    const int* __restrict__ trg_tok,
    float* __restrict__ pm, float* __restrict__ ps, float* __restrict__ tgtlog) {
  __shared__ float As[16][68];
  __shared__ float Bs[16][68];
  __shared__ float Cs[64][65];
  int tid = threadIdx.x;
  int tm = tid >> 4, tn = tid & 15;
  int row0 = blockIdx.x * 64;
  int col0 = blockIdx.y * 64;
  float acc[4][4] = {};
  for (int k0 = 0; k0 < 2048; k0 += 16) {
#pragma unroll
    for (int i = 0; i < 4; i++) {
      int r = tm + i * 16;
      int gm = row0 + r;
      As[tn][r] = (gm < NR) ? Y[(size_t)gm * 2048 + k0 + tn] : 0.f;
      Bs[tn][r] = Wo[(size_t)(col0 + r) * 2048 + k0 + tn];
    }
    __syncthreads();
#pragma unroll
    for (int k = 0; k < 16; k++) {
      float a4[4], b4[4];
#pragma unroll
      for (int i = 0; i < 4; i++) a4[i] = As[k][tm * 4 + i];
#pragma unroll
      for (int j = 0; j < 4; j++) b4[j] = Bs[k][tn * 4 + j];
#pragma unroll
      for (int i = 0; i < 4; i++)
#pragma unroll
        for (int j = 0; j < 4; j++) acc[i][j] += a4[i] * b4[j];
    }
    __syncthreads();
  }
#pragma unroll
  for (int i = 0; i < 4; i++)
#pragma unroll
    for (int j = 0; j < 4; j++)
      Cs[tm * 4 + i][tn * 4 + j] = acc[i][j] + bo[col0 + tn * 4 + j];
  __syncthreads();
  if (tid < 64) {
    int gm = row0 + tid;
    if (gm < NR) {
      float m = -1e30f;
#pragma unroll 8
      for (int c = 0; c < 64; c++) m = fmaxf(m, Cs[tid][c]);
      float s = 0.f;
#pragma unroll 8
      for (int c = 0; c < 64; c++) s += expf(Cs[tid][c] - m);
      pm[(size_t)blockIdx.y * NR + gm] = m;
      ps[(size_t)blockIdx.y * NR + gm] = s;
      int t = gm >> 5, b = gm & 31;
      int tgt = trg_tok[b * NT + t + 1];
      int c = tgt - col0;
      if (c >= 0 && c < 64) tgtlog[gm] = Cs[tid][c];
    }
  }
}

// ---------- merge per-chunk lse partials, apply mask ----------
__global__ void lse_combine_kernel(const float* __restrict__ pm, const float* __restrict__ ps,
                                   const float* __restrict__ tgtlog, const int* __restrict__ trg_lens,
                                   float* __restrict__ rowval) {
  int r = blockIdx.x * blockDim.x + threadIdx.x;
  if (r >= NR) return;
  float m = -1e30f;
  for (int i = 0; i < NCT; i++) m = fmaxf(m, pm[(size_t)i * NR + r]);
  float s = 0.f;
  for (int i = 0; i < NCT; i++) s += ps[(size_t)i * NR + r] * expf(pm[(size_t)i * NR + r] - m);
  float lse = m + logf(s);
  int t = r >> 5, b = r & 31;
  float v = tgtlog[r] - lse;  // log_softmax at target
  rowval[r] = ((t + 1) < trg_lens[b]) ? v : 0.f;
}

__global__ void final_reduce_kernel(const float* __restrict__ rowval, float* __restrict__ out) {
  __shared__ float sm[256];
  float s = 0.f;
  for (int i = threadIdx.x; i < NR; i += 256) s += rowval[i];
  sm[threadIdx.x] = s;
  __syncthreads();
  for (int off = 128; off > 0; off >>= 1) {
    if (threadIdx.x < off) sm[threadIdx.x] += sm[threadIdx.x + off];
    __syncthreads();
  }
  if (threadIdx.x == 0) out[0] = sm[0];
}

extern "C" void kernel_launch(void* const* d_in, const int* in_sizes, int n_in,
                              void* d_out, int out_size, void* d_ws, size_t ws_size,
                              hipStream_t stream) {
  const int* src_tokens = (const int*)d_in[0];
  const int* src_lens = (const int*)d_in[1];
  const int* trg_tokens = (const int*)d_in[2];
  const int* trg_lens = (const int*)d_in[3];
  const float* src_emb = (const float*)d_in[4];
  const float* trg_emb = (const float*)d_in[5];
  const float* We_ih = (const float*)d_in[6];
  const float* We_hh = (const float*)d_in[7];
  const float* be_ih = (const float*)d_in[8];
  const float* be_hh = (const float*)d_in[9];
  const float* Wr_ih = (const float*)d_in[10];
  const float* Wr_hh = (const float*)d_in[11];
  const float* br_ih = (const float*)d_in[12];
  const float* br_hh = (const float*)d_in[13];
  const float* Wd_ih = (const float*)d_in[14];
  const float* Wd_hh = (const float*)d_in[15];
  const float* bd_ih = (const float*)d_in[16];
  const float* bd_hh = (const float*)d_in[17];
  const float* W_out = (const float*)d_in[18];
  const float* b_out = (const float*)d_in[19];

  float* w = (float*)d_ws;
  float* xsrc = w;  w += 2048 * 512;
  float* Aef = w;   w += 2048 * 2048;
  float* Aer = w;   w += 2048 * 2048;
  float* ss = w;    w += 32 * 64 * 1024;
  float* ehf0 = w;  w += 32 * 512;
  float* ehf1 = w;  w += 32 * 512;
  float* ecf0 = w;  w += 32 * 512;
  float* ecf1 = w;  w += 32 * 512;
  float* ehr0 = w;  w += 32 * 512;
  float* ehr1 = w;  w += 32 * 512;
  float* ecr0 = w;  w += 32 * 512;
  float* ecr1 = w;  w += 32 * 512;
  float* xtrg = w;  w += 2016 * 512;
  float* Ad = w;    w += 2016 * 4096;
  float* dh0 = w;   w += 32 * 1024;
  float* dh1 = w;   w += 32 * 1024;
  float* dc0 = w;   w += 32 * 1024;
  float* dc1 = w;   w += 32 * 1024;
  float* Yb = w;    w += 2016 * 2048;
  float* pm = w;    w += NCT * NR;
  float* ps = w;    w += NCT * NR;
  float* tgtlog = w; w += NR;
  float* rowval = w; w += NR;

  // gathers
  gather_src_kernel<<<(2048 * 128 + 255) / 256, 256, 0, stream>>>(src_tokens, src_emb, xsrc);
  gather_trg_kernel<<<(2016 * 128 + 255) / 256, 256, 0, stream>>>(trg_tokens, trg_emb, xtrg);

  // batched input-gate GEMMs (+ both biases folded in)
  gemm_abT_kernel<<<dim3(32, 32), 256, 0, stream>>>(xsrc, We_ih, be_ih, be_hh, Aef, 2048, 2048, 512);
  gemm_abT_kernel<<<dim3(32, 32), 256, 0, stream>>>(xsrc, Wr_ih, br_ih, br_hh, Aer, 2048, 2048, 512);
  gemm_abT_kernel<<<dim3(64, 32), 256, 0, stream>>>(xtrg, Wd_ih, bd_ih, bd_hh, Ad, 2016, 4096, 512);

  // zero encoder h/c state buffers (8 x 16384 contiguous)
  zero_kernel<<<(131072 + 255) / 256, 256, 0, stream>>>(ehf0, 131072);

  // encoder recurrence (both LSTMs fused per step)
  float* hf[2] = {ehf0, ehf1};
  float* cf[2] = {ecf0, ecf1};
  float* hr[2] = {ehr0, ehr1};
  float* cr[2] = {ecr0, ecr1};
  int cur = 0;
  for (int t = 0; t < NS; t++) {
    enc_step_kernel<<<128, 256, 0, stream>>>(Aef, Aer, We_hh, Wr_hh,
                                             hf[cur], cf[cur], hf[1 - cur], cf[1 - cur],
                                             hr[cur], cr[cur], hr[1 - cur], cr[1 - cur], ss, t);
    cur ^= 1;
  }

  // decoder init + recurrence
  dec_init_kernel<<<128, 256, 0, stream>>>(ss, src_lens, dh0, dc0);
  float* dh[2] = {dh0, dh1};
  float* dc[2] = {dc0, dc1};
  cur = 0;
  for (int t = 0; t < NT - 1; t++) {
    dec_step_kernel<<<128, 256, 0, stream>>>(Ad, Wd_hh, dh[cur], dc[cur], dh[1 - cur], dc[1 - cur], Yb, t);
    cur ^= 1;
  }

  // batched attention (ctx only feeds logits, not the recurrence)
  attn_kernel<<<NR, 256, 0, stream>>>(Yb, ss, src_lens);

  // fused logits GEMM + chunked logsumexp
  gemmlse_kernel<<<dim3(32, NCT), 256, 0, stream>>>(Yb, W_out, b_out, trg_tokens, pm, ps, tgtlog);
  lse_combine_kernel<<<(NR + 255) / 256, 256, 0, stream>>>(pm, ps, tgtlog, trg_lens, rowval);
  final_reduce_kernel<<<1, 256, 0, stream>>>(rowval, (float*)d_out);
}

// Round 2
// 4055.715 us; speedup vs baseline: 5.1556x; 5.1556x over previous
//
#include <hip/hip_runtime.h>
#include <math.h>

#define NB 32      // batch
#define NS 64      // src len
#define NT 64      // trg len
#define NE 512     // embed
#define NH 512     // enc hidden
#define NHD 1024   // dec hidden (2H)
#define NV 32000   // vocab
#define NR 2016    // decoder rows = (NT-1)*NB
#define NCT 250    // col tiles in gemmlse = NV/128

typedef __bf16 bf16x8 __attribute__((ext_vector_type(8)));
typedef float f32x4 __attribute__((ext_vector_type(4)));

__device__ __forceinline__ float sigmf(float x) { return 1.f / (1.f + expf(-x)); }

__device__ __forceinline__ unsigned short f2bf(float f) {
  union { float f; unsigned u; } v; v.f = f;
  unsigned r = v.u + 0x7FFFu + ((v.u >> 16) & 1u);
  return (unsigned short)(r >> 16);
}

// ---------- embedding gathers ----------
__global__ void gather_src_kernel(const int* tok, const float* emb, float* out) {
  int idx = blockIdx.x * blockDim.x + threadIdx.x;  // over 2048*128 float4
  int m = idx >> 7;
  int e4 = idx & 127;
  if (m >= NB * NS) return;
  const float4* src = (const float4*)(emb + (size_t)tok[m] * NE);
  ((float4*)(out + (size_t)m * NE))[e4] = src[e4];
}

__global__ void gather_trg_kernel(const int* tok, const float* emb, float* out) {
  int idx = blockIdx.x * blockDim.x + threadIdx.x;  // over 2016*128 float4
  int m = idx >> 7;
  int e4 = idx & 127;
  if (m >= NR) return;
  int t = m >> 5, b = m & 31;  // row m = t*32 + b
  int token = tok[b * NT + t];
  const float4* src = (const float4*)(emb + (size_t)token * NE);
  ((float4*)(out + (size_t)m * NE))[e4] = src[e4];
}

__global__ void zero_u32_kernel(unsigned* p, int n) {
  int i = blockIdx.x * blockDim.x + threadIdx.x;
  if (i < n) p[i] = 0u;
}

// ---------- f32 -> bf16 (RNE), 8 elems/thread ----------
__global__ void f32_to_bf16_kernel(const float* __restrict__ in, unsigned short* __restrict__ out, long n) {
  long i = ((long)blockIdx.x * 256 + threadIdx.x) * 8;
  if (i >= n) return;
  float4 a = *(const float4*)(in + i);
  float4 b = *(const float4*)(in + i + 4);
  union { unsigned short s[8]; uint4 v; } u;
  u.s[0] = f2bf(a.x); u.s[1] = f2bf(a.y); u.s[2] = f2bf(a.z); u.s[3] = f2bf(a.w);
  u.s[4] = f2bf(b.x); u.s[5] = f2bf(b.y); u.s[6] = f2bf(b.z); u.s[7] = f2bf(b.w);
  *(uint4*)(out + i) = u.v;
}

// ---------- generic fp32 GEMM: C[m,n] = sum_k A[m,k]*B[n,k] + b0[n] + b1[n] ----------
__global__ __launch_bounds__(256) void gemm_abT_kernel(
    const float* __restrict__ A, const float* __restrict__ Bm,
    const float* __restrict__ b0, const float* __restrict__ b1,
    float* __restrict__ C, int M, int N, int K) {
  __shared__ float As[16][68];
  __shared__ float Bs[16][68];
  int tid = threadIdx.x;
  int tm = tid >> 4, tn = tid & 15;
  int row0 = blockIdx.y * 64;
  int col0 = blockIdx.x * 64;
  float acc[4][4] = {};
  for (int k0 = 0; k0 < K; k0 += 16) {
#pragma unroll
    for (int i = 0; i < 4; i++) {
      int r = tm + i * 16;
      int gm = row0 + r;
      As[tn][r] = (gm < M) ? A[(size_t)gm * K + k0 + tn] : 0.f;
      Bs[tn][r] = Bm[(size_t)(col0 + r) * K + k0 + tn];
    }
    __syncthreads();
#pragma unroll
    for (int k = 0; k < 16; k++) {
      float a4[4], b4[4];
#pragma unroll
      for (int i = 0; i < 4; i++) a4[i] = As[k][tm * 4 + i];
#pragma unroll
      for (int j = 0; j < 4; j++) b4[j] = Bs[k][tn * 4 + j];
#pragma unroll
      for (int i = 0; i < 4; i++)
#pragma unroll
        for (int j = 0; j < 4; j++) acc[i][j] += a4[i] * b4[j];
    }
    __syncthreads();
  }
#pragma unroll
  for (int i = 0; i < 4; i++) {
    int gm = row0 + tm * 4 + i;
    if (gm >= M) continue;
#pragma unroll
    for (int j = 0; j < 4; j++) {
      int gn = col0 + tn * 4 + j;
      C[(size_t)gm * N + gn] = acc[i][j] + b0[gn] + b1[gn];
    }
  }
}

// ---------- encoder step (MFMA, both LSTMs, fused gates) ----------
// grid 64 blocks x 64 thr. block = (lstm = bid>>5, jt = bid&31); computes all 4 gates
// for 16 j-cols x 32 batches, K=512.
__global__ __launch_bounds__(64) void enc_step_mfma(
    const unsigned short* __restrict__ hf, const unsigned short* __restrict__ hr,
    const unsigned short* __restrict__ W,  // [4096][512] bf16 (0..2047 fwd, 2048.. rev)
    const float* __restrict__ Aef, const float* __restrict__ Aer,
    float* __restrict__ cf, float* __restrict__ cr,
    unsigned short* __restrict__ hf_out, unsigned short* __restrict__ hr_out,
    float* __restrict__ ss, int t) {
  int tid = threadIdx.x;
  int r = tid & 15, q = tid >> 4;
  int lstm = blockIdx.x >> 5;
  int jt = blockIdx.x & 31;
  int jcol = jt * 16 + r;
  const unsigned short* h = lstm ? hr : hf;
  unsigned short* hout = lstm ? hr_out : hf_out;
  float* cst = lstm ? cr : cf;
  const float* Ae = lstm ? Aer : Aef;
  f32x4 acc[4][2] = {};
  int koff = q * 8;
  for (int ks = 0; ks < NH; ks += 32) {
    bf16x8 a0 = *(const bf16x8*)(h + (size_t)r * NH + ks + koff);
    bf16x8 a1 = *(const bf16x8*)(h + (size_t)(16 + r) * NH + ks + koff);
#pragma unroll
    for (int g = 0; g < 4; g++) {
      bf16x8 b = *(const bf16x8*)(W + (size_t)(lstm * 2048 + g * 512 + jcol) * NH + ks + koff);
      acc[g][0] = __builtin_amdgcn_mfma_f32_16x16x32_bf16(a0, b, acc[g][0], 0, 0, 0);
      acc[g][1] = __builtin_amdgcn_mfma_f32_16x16x32_bf16(a1, b, acc[g][1], 0, 0, 0);
    }
  }
#pragma unroll
  for (int mt = 0; mt < 2; mt++) {
#pragma unroll
    for (int j = 0; j < 4; j++) {
      int b = mt * 16 + q * 4 + j;
      size_t base = ((size_t)b * NS + t) * 2048;
      float gi = acc[0][mt][j] + Ae[base + jcol];
      float gf = acc[1][mt][j] + Ae[base + 512 + jcol];
      float gg = acc[2][mt][j] + Ae[base + 1024 + jcol];
      float go = acc[3][mt][j] + Ae[base + 1536 + jcol];
      float c = sigmf(gf) * cst[b * NH + jcol] + sigmf(gi) * tanhf(gg);
      float hv = sigmf(go) * tanhf(c);
      cst[b * NH + jcol] = c;
      hout[b * NH + jcol] = f2bf(hv);
      ss[((size_t)b * NS + t) * NHD + lstm * 512 + jcol] = hv;
    }
  }
}

// ---------- decoder init: h0 = src_states[b, len-1, :] (bf16), c0 = 0 ----------
__global__ void dec_init_kernel(const float* __restrict__ ss, const int* __restrict__ src_lens,
                                unsigned short* __restrict__ hbf0, float* __restrict__ cc) {
  int idx = blockIdx.x * 256 + threadIdx.x;  // 32*1024
  int b = idx >> 10, j = idx & 1023;
  int s = src_lens[b] - 1;
  float h = ss[((size_t)b * NS + s) * NHD + j];
  hbf0[idx] = f2bf(h);
  cc[idx] = 0.f;
}

// ---------- decoder step (MFMA, fused gates) ----------
// grid 64 blocks x 64 thr. block jt: 16 j-cols x all 4 gates x 32 batches, K=1024.
__global__ __launch_bounds__(64) void dec_step_mfma(
    const unsigned short* __restrict__ hbf, const unsigned short* __restrict__ W,  // [4096][1024]
    const float* __restrict__ Ad, float* __restrict__ cc,
    unsigned short* __restrict__ hout, float* __restrict__ hs,
    unsigned short* __restrict__ Ybf, int t) {
  int tid = threadIdx.x;
  int r = tid & 15, q = tid >> 4;
  int jt = blockIdx.x;
  int jcol = jt * 16 + r;
  f32x4 acc[4][2] = {};
  int koff = q * 8;
  for (int ks = 0; ks < NHD; ks += 32) {
    bf16x8 a0 = *(const bf16x8*)(hbf + (size_t)r * NHD + ks + koff);
    bf16x8 a1 = *(const bf16x8*)(hbf + (size_t)(16 + r) * NHD + ks + koff);
#pragma unroll
    for (int g = 0; g < 4; g++) {
      bf16x8 b = *(const bf16x8*)(W + (size_t)(g * 1024 + jcol) * NHD + ks + koff);
      acc[g][0] = __builtin_amdgcn_mfma_f32_16x16x32_bf16(a0, b, acc[g][0], 0, 0, 0);
      acc[g][1] = __builtin_amdgcn_mfma_f32_16x16x32_bf16(a1, b, acc[g][1], 0, 0, 0);
    }
  }
#pragma unroll
  for (int mt = 0; mt < 2; mt++) {
#pragma unroll
    for (int j = 0; j < 4; j++) {
      int b = mt * 16 + q * 4 + j;
      const float* ad = Ad + (size_t)(t * NB + b) * 4096;
      float gi = acc[0][mt][j] + ad[jcol];
      float gf = acc[1][mt][j] + ad[1024 + jcol];
      float gg = acc[2][mt][j] + ad[2048 + jcol];
      float go = acc[3][mt][j] + ad[3072 + jcol];
      float c = sigmf(gf) * cc[b * NHD + jcol] + sigmf(gi) * tanhf(gg);
      float hv = sigmf(go) * tanhf(c);
      cc[b * NHD + jcol] = c;
      hout[b * NHD + jcol] = f2bf(hv);
      int rowY = t * NB + b;
      hs[(size_t)rowY * NHD + jcol] = hv;
      Ybf[(size_t)rowY * 2048 + jcol] = f2bf(hv);
    }
  }
}

// ---------- batched attention: block per (t,b) row, ctx -> Ybf[:,1024:2048] bf16 ----------
__global__ __launch_bounds__(256) void attn_kernel(const float* __restrict__ hs,
                                                   const float* __restrict__ ss,
                                                   const int* __restrict__ src_lens,
                                                   unsigned short* __restrict__ Ybf) {
  __shared__ __align__(16) float hsh[NHD];
  __shared__ float sc[NS];
  __shared__ float att[NS];
  int r = blockIdx.x;
  int b = r & 31;
  int tid = threadIdx.x;
  for (int i = tid; i < NHD; i += 256) hsh[i] = hs[(size_t)r * NHD + i];
  __syncthreads();
  {
    int s = tid >> 2, q = tid & 3;
    const float4* row = (const float4*)(ss + ((size_t)b * NS + s) * NHD);
    const float4* h4 = (const float4*)hsh;
    float p = 0.f;
    for (int k = q * 64; k < q * 64 + 64; k++) {
      float4 hh = h4[k];
      float4 rr = row[k];
      p += hh.x * rr.x + hh.y * rr.y + hh.z * rr.z + hh.w * rr.w;
    }
    p += __shfl_xor(p, 1);
    p += __shfl_xor(p, 2);
    if (q == 0) sc[s] = (s < src_lens[b]) ? p : -1e9f;
  }
  __syncthreads();
  if (tid < 64) {
    float v = sc[tid];
    float m = v;
#pragma unroll
    for (int off = 1; off < 64; off <<= 1) m = fmaxf(m, __shfl_xor(m, off));
    float e = expf(v - m);
    float ssum = e;
#pragma unroll
    for (int off = 1; off < 64; off <<= 1) ssum += __shfl_xor(ssum, off);
    att[tid] = e / ssum;
  }
  __syncthreads();
  float acc0 = 0, acc1 = 0, acc2 = 0, acc3 = 0;
  int d = tid * 4;
  for (int s2 = 0; s2 < NS; s2++) {
    float a = att[s2];
    const float4 rr = *(const float4*)(ss + ((size_t)b * NS + s2) * NHD + d);
    acc0 += a * rr.x;
    acc1 += a * rr.y;
    acc2 += a * rr.z;
    acc3 += a * rr.w;
  }
  ushort4 o;
  o.x = f2bf(acc0); o.y = f2bf(acc1); o.z = f2bf(acc2); o.w = f2bf(acc3);
  *(ushort4*)(Ybf + (size_t)r * 2048 + NHD + d) = o;
}

// ---------- MFMA logits GEMM + fused chunked logsumexp ----------
// grid (16 row-tiles, 250 col-tiles), 256 thr (4 waves, 2x2 of 64x64).
__global__ __launch_bounds__(256) void gemmlse_mfma(
    const unsigned short* __restrict__ Y,   // [2016][2048] bf16
    const unsigned short* __restrict__ Wo,  // [32000][2048] bf16
    const float* __restrict__ bo, const int* __restrict__ trg_tok,
    float* __restrict__ pm, float* __restrict__ ps, float* __restrict__ tgtlog) {
  __shared__ float Cs[128][129];
  __shared__ float bsh[128];
  int tid = threadIdx.x;
  int wave = tid >> 6, lane = tid & 63;
  int r = lane & 15, q = lane >> 4;
  int mh = wave >> 1, nh = wave & 1;
  int bm = blockIdx.x, bn = blockIdx.y;
  int rowbase = bm * 128 + mh * 64;
  int colbase = bn * 128 + nh * 64;
  f32x4 acc[4][4] = {};
  int koff = q * 8;
  for (int k0 = 0; k0 < 2048; k0 += 32) {
    bf16x8 a[4], b[4];
#pragma unroll
    for (int mt = 0; mt < 4; mt++) {
      int rb = rowbase + mt * 16;
      int rload = (rb < NR) ? rb : 0;  // clamp; garbage rows are ignored in epilogue
      a[mt] = *(const bf16x8*)(Y + (size_t)(rload + r) * 2048 + k0 + koff);
    }
#pragma unroll
    for (int nt = 0; nt < 4; nt++)
      b[nt] = *(const bf16x8*)(Wo + (size_t)(colbase + nt * 16 + r) * 2048 + k0 + koff);
#pragma unroll
    for (int mt = 0; mt < 4; mt++)
#pragma unroll
      for (int nt = 0; nt < 4; nt++)
        acc[mt][nt] = __builtin_amdgcn_mfma_f32_16x16x32_bf16(a[mt], b[nt], acc[mt][nt], 0, 0, 0);
  }
  if (tid < 128) bsh[tid] = bo[bn * 128 + tid];
#pragma unroll
  for (int mt = 0; mt < 4; mt++)
#pragma unroll
    for (int nt = 0; nt < 4; nt++)
#pragma unroll
      for (int j = 0; j < 4; j++)
        Cs[mh * 64 + mt * 16 + q * 4 + j][nh * 64 + nt * 16 + r] = acc[mt][nt][j];
  __syncthreads();
  if (tid < 128) {
    int gm = bm * 128 + tid;
    if (gm < NR) {
      float m = -1e30f;
#pragma unroll 8
      for (int c = 0; c < 128; c++) m = fmaxf(m, Cs[tid][c] + bsh[c]);
      float s = 0.f;
#pragma unroll 8
      for (int c = 0; c < 128; c++) s += expf(Cs[tid][c] + bsh[c] - m);
      pm[(size_t)bn * NR + gm] = m;
      ps[(size_t)bn * NR + gm] = s;
      int tt = gm >> 5, b = gm & 31;
      int tgt = trg_tok[b * NT + tt + 1];
      int c = tgt - bn * 128;
      if (c >= 0 && c < 128) tgtlog[gm] = Cs[tid][c] + bsh[c];
    }
  }
}

// ---------- merge per-chunk lse partials, apply mask ----------
__global__ void lse_combine_kernel(const float* __restrict__ pm, const float* __restrict__ ps,
                                   const float* __restrict__ tgtlog, const int* __restrict__ trg_lens,
                                   float* __restrict__ rowval) {
  int r = blockIdx.x * blockDim.x + threadIdx.x;
  if (r >= NR) return;
  float m = -1e30f;
  for (int i = 0; i < NCT; i++) m = fmaxf(m, pm[(size_t)i * NR + r]);
  float s = 0.f;
  for (int i = 0; i < NCT; i++) s += ps[(size_t)i * NR + r] * expf(pm[(size_t)i * NR + r] - m);
  float lse = m + logf(s);
  int t = r >> 5, b = r & 31;
  float v = tgtlog[r] - lse;
  rowval[r] = ((t + 1) < trg_lens[b]) ? v : 0.f;
}

__global__ void final_reduce_kernel(const float* __restrict__ rowval, float* __restrict__ out) {
  __shared__ float sm[256];
  float s = 0.f;
  for (int i = threadIdx.x; i < NR; i += 256) s += rowval[i];
  sm[threadIdx.x] = s;
  __syncthreads();
  for (int off = 128; off > 0; off >>= 1) {
    if (threadIdx.x < off) sm[threadIdx.x] += sm[threadIdx.x + off];
    __syncthreads();
  }
  if (threadIdx.x == 0) out[0] = sm[0];
}

extern "C" void kernel_launch(void* const* d_in, const int* in_sizes, int n_in,
                              void* d_out, int out_size, void* d_ws, size_t ws_size,
                              hipStream_t stream) {
  const int* src_tokens = (const int*)d_in[0];
  const int* src_lens = (const int*)d_in[1];
  const int* trg_tokens = (const int*)d_in[2];
  const int* trg_lens = (const int*)d_in[3];
  const float* src_emb = (const float*)d_in[4];
  const float* trg_emb = (const float*)d_in[5];
  const float* We_ih = (const float*)d_in[6];
  const float* We_hh = (const float*)d_in[7];
  const float* be_ih = (const float*)d_in[8];
  const float* be_hh = (const float*)d_in[9];
  const float* Wr_ih = (const float*)d_in[10];
  const float* Wr_hh = (const float*)d_in[11];
  const float* br_ih = (const float*)d_in[12];
  const float* br_hh = (const float*)d_in[13];
  const float* Wd_ih = (const float*)d_in[14];
  const float* Wd_hh = (const float*)d_in[15];
  const float* bd_ih = (const float*)d_in[16];
  const float* bd_hh = (const float*)d_in[17];
  const float* W_out = (const float*)d_in[18];
  const float* b_out = (const float*)d_in[19];

  char* base = (char*)d_ws;
  size_t off = 0;
  auto alloc = [&](size_t bytes) -> char* {
    char* p = base + off;
    off += (bytes + 255) & ~(size_t)255;
    return p;
  };
  float* xsrc = (float*)alloc((size_t)2048 * 512 * 4);
  float* xtrg = (float*)alloc((size_t)NR * 512 * 4);
  float* Aef = (float*)alloc((size_t)2048 * 2048 * 4);
  float* Aer = (float*)alloc((size_t)2048 * 2048 * 4);
  float* Ad  = (float*)alloc((size_t)NR * 4096 * 4);
  float* ss  = (float*)alloc((size_t)NB * NS * NHD * 4);
  float* hs_dec = (float*)alloc((size_t)NR * NHD * 4);
  unsigned short* Ybf = (unsigned short*)alloc((size_t)NR * 2048 * 2);
  unsigned short* Wbf_e = (unsigned short*)alloc((size_t)4096 * 512 * 2);
  unsigned short* Wbf_d = (unsigned short*)alloc((size_t)4096 * 1024 * 2);
  unsigned short* Wobf = (unsigned short*)alloc((size_t)NV * 2048 * 2);
  char* encstate = alloc(196608);  // hbf_f0(32K) hbf_r0(32K) cf(64K) cr(64K) -- zeroed as one span
  unsigned short* hbf_f0 = (unsigned short*)encstate;
  unsigned short* hbf_r0 = (unsigned short*)(encstate + 32768);
  float* cf = (float*)(encstate + 65536);
  float* cr = (float*)(encstate + 131072);
  unsigned short* hbf_f1 = (unsigned short*)alloc(32768);
  unsigned short* hbf_r1 = (unsigned short*)alloc(32768);
  unsigned short* hbf_d0 = (unsigned short*)alloc(65536);
  unsigned short* hbf_d1 = (unsigned short*)alloc(65536);
  float* cc = (float*)alloc(131072);
  float* pm = (float*)alloc((size_t)NCT * NR * 4);
  float* ps = (float*)alloc((size_t)NCT * NR * 4);
  float* tgtlog = (float*)alloc((size_t)NR * 4);
  float* rowval = (float*)alloc((size_t)NR * 4);

  // gathers
  gather_src_kernel<<<(2048 * 128 + 255) / 256, 256, 0, stream>>>(src_tokens, src_emb, xsrc);
  gather_trg_kernel<<<(NR * 128 + 255) / 256, 256, 0, stream>>>(trg_tokens, trg_emb, xtrg);

  // batched input-gate GEMMs (fp32, biases folded)
  gemm_abT_kernel<<<dim3(32, 32), 256, 0, stream>>>(xsrc, We_ih, be_ih, be_hh, Aef, 2048, 2048, 512);
  gemm_abT_kernel<<<dim3(32, 32), 256, 0, stream>>>(xsrc, Wr_ih, br_ih, br_hh, Aer, 2048, 2048, 512);
  gemm_abT_kernel<<<dim3(64, 32), 256, 0, stream>>>(xtrg, Wd_ih, bd_ih, bd_hh, Ad, NR, 4096, 512);

  // weight conversions to bf16 (once per launch)
  f32_to_bf16_kernel<<<512, 256, 0, stream>>>(We_hh, Wbf_e, (long)2048 * 512);
  f32_to_bf16_kernel<<<512, 256, 0, stream>>>(Wr_hh, Wbf_e + (size_t)2048 * 512, (long)2048 * 512);
  f32_to_bf16_kernel<<<2048, 256, 0, stream>>>(Wd_hh, Wbf_d, (long)4096 * 1024);
  f32_to_bf16_kernel<<<32000, 256, 0, stream>>>(W_out, Wobf, (long)NV * 2048);

  // zero encoder state (hbf_f0, hbf_r0, cf, cr)
  zero_u32_kernel<<<192, 256, 0, stream>>>((unsigned*)encstate, 49152);

  // encoder recurrence
  unsigned short* hfp[2] = {hbf_f0, hbf_f1};
  unsigned short* hrp[2] = {hbf_r0, hbf_r1};
  for (int t = 0; t < NS; t++) {
    enc_step_mfma<<<64, 64, 0, stream>>>(hfp[t & 1], hrp[t & 1], Wbf_e, Aef, Aer, cf, cr,
                                         hfp[(t + 1) & 1], hrp[(t + 1) & 1], ss, t);
  }

  // decoder init + recurrence
  dec_init_kernel<<<128, 256, 0, stream>>>(ss, src_lens, hbf_d0, cc);
  unsigned short* hd[2] = {hbf_d0, hbf_d1};
  for (int t = 0; t < NT - 1; t++) {
    dec_step_mfma<<<64, 64, 0, stream>>>(hd[t & 1], Wbf_d, Ad, cc, hd[(t + 1) & 1], hs_dec, Ybf, t);
  }

  // batched attention (ctx only feeds logits)
  attn_kernel<<<NR, 256, 0, stream>>>(hs_dec, ss, src_lens, Ybf);

  // fused bf16-MFMA logits GEMM + chunked logsumexp
  gemmlse_mfma<<<dim3(16, NCT), 256, 0, stream>>>(Ybf, Wobf, b_out, trg_tokens, pm, ps, tgtlog);
  lse_combine_kernel<<<(NR + 255) / 256, 256, 0, stream>>>(pm, ps, tgtlog, trg_lens, rowval);
  final_reduce_kernel<<<1, 256, 0, stream>>>(rowval, (float*)d_out);
}

// Round 3
// 4040.821 us; speedup vs baseline: 5.1746x; 1.0037x over previous
//
#include <hip/hip_runtime.h>
#include <math.h>

#define NB 32      // batch
#define NS 64      // src len
#define NT 64      // trg len
#define NHD 1024   // dec hidden
#define NV 32000
#define NR 2016    // (NT-1)*NB
#define NCT 250    // 32000/128
#define RECB 64    // blocks in persistent recurrence kernel

typedef unsigned short u16;
typedef __bf16 bf16x8 __attribute__((ext_vector_type(8)));
typedef float f32x4 __attribute__((ext_vector_type(4)));
#define MFMA16 __builtin_amdgcn_mfma_f32_16x16x32_bf16

__device__ __forceinline__ float sigmf(float x) { return 1.f / (1.f + expf(-x)); }
__device__ __forceinline__ u16 f2bf(float f) {
  union { float f; unsigned u; } v; v.f = f;
  unsigned r = v.u + 0x7FFFu + ((v.u >> 16) & 1u);
  return (u16)(r >> 16);
}

// ---------------- device-scope grid barrier (all RECB blocks co-resident: 1 block/CU, 64 <= 256 CUs)
__device__ __forceinline__ void gridbar(unsigned* bar, int nblk) {
  __threadfence();   // release my block's global writes
  __syncthreads();
  if (threadIdx.x == 0) {
    unsigned* cnt = bar;
    unsigned* gen = bar + 1;
    unsigned g = __hip_atomic_load(gen, __ATOMIC_RELAXED, __HIP_MEMORY_SCOPE_AGENT);
    unsigned v = __hip_atomic_fetch_add(cnt, 1u, __ATOMIC_ACQ_REL, __HIP_MEMORY_SCOPE_AGENT);
    if (v == (unsigned)(nblk - 1)) {
      __hip_atomic_store(cnt, 0u, __ATOMIC_RELAXED, __HIP_MEMORY_SCOPE_AGENT);
      __hip_atomic_fetch_add(gen, 1u, __ATOMIC_RELEASE, __HIP_MEMORY_SCOPE_AGENT);
    } else {
      while (__hip_atomic_load(gen, __ATOMIC_ACQUIRE, __HIP_MEMORY_SCOPE_AGENT) == g)
        __builtin_amdgcn_s_sleep(4);
    }
  }
  __syncthreads();
  __threadfence();   // acquire: see remote writes
}

__global__ void init_bar_kernel(unsigned* bar) {
  if (threadIdx.x < 2) bar[threadIdx.x] = 0u;
}

// ---------------- gathers (emit bf16) ----------------
__global__ void gather_src_bf16(const int* tok, const float* emb, u16* out) {
  int idx = blockIdx.x * 256 + threadIdx.x;  // 2048*64
  if (idx >= 2048 * 64) return;
  int m = idx >> 6, c8 = (idx & 63) * 8;
  const float4* s = (const float4*)(emb + (size_t)tok[m] * 512 + c8);
  float4 a = s[0], b = s[1];
  union { u16 h[8]; uint4 v; } u;
  u.h[0]=f2bf(a.x); u.h[1]=f2bf(a.y); u.h[2]=f2bf(a.z); u.h[3]=f2bf(a.w);
  u.h[4]=f2bf(b.x); u.h[5]=f2bf(b.y); u.h[6]=f2bf(b.z); u.h[7]=f2bf(b.w);
  *(uint4*)(out + (size_t)m * 512 + c8) = u.v;
}

__global__ void gather_trg_bf16(const int* tok, const float* emb, u16* out) {
  int idx = blockIdx.x * 256 + threadIdx.x;  // NR*64
  if (idx >= NR * 64) return;
  int m = idx >> 6, c8 = (idx & 63) * 8;
  int t = m >> 5, b = m & 31;  // row m = t*32 + b
  int token = tok[b * NT + t];
  const float4* s = (const float4*)(emb + (size_t)token * 512 + c8);
  float4 a = s[0], bb = s[1];
  union { u16 h[8]; uint4 v; } u;
  u.h[0]=f2bf(a.x); u.h[1]=f2bf(a.y); u.h[2]=f2bf(a.z); u.h[3]=f2bf(a.w);
  u.h[4]=f2bf(bb.x); u.h[5]=f2bf(bb.y); u.h[6]=f2bf(bb.z); u.h[7]=f2bf(bb.w);
  *(uint4*)(out + (size_t)m * 512 + c8) = u.v;
}

// ---------------- f32 -> bf16 ----------------
__global__ void cvt_bf16_kernel(const float* __restrict__ in, u16* __restrict__ out, long n) {
  long i = ((long)blockIdx.x * 256 + threadIdx.x) * 8;
  if (i >= n) return;
  float4 a = *(const float4*)(in + i);
  float4 b = *(const float4*)(in + i + 4);
  union { u16 h[8]; uint4 v; } u;
  u.h[0]=f2bf(a.x); u.h[1]=f2bf(a.y); u.h[2]=f2bf(a.z); u.h[3]=f2bf(a.w);
  u.h[4]=f2bf(b.x); u.h[5]=f2bf(b.y); u.h[6]=f2bf(b.z); u.h[7]=f2bf(b.w);
  *(uint4*)(out + i) = u.v;
}

// ---------------- bf16 MFMA GEMM: C[m][n] = sum_k A[m][k] B[n][k] + b0[n] + b1[n] (fp32 out)
__global__ __launch_bounds__(256) void mfma_gemm_bias(
    const u16* __restrict__ A, const u16* __restrict__ Bm,
    const float* __restrict__ b0, const float* __restrict__ b1,
    float* __restrict__ C, int M, int N, int K) {
  int tid = threadIdx.x, wave = tid >> 6, lane = tid & 63;
  int r = lane & 15, q = lane >> 4;
  int mh = wave >> 1, nh = wave & 1;
  int rowbase = blockIdx.x * 128 + mh * 64;
  int colbase = blockIdx.y * 128 + nh * 64;
  f32x4 acc[4][4] = {};
  for (int k0 = 0; k0 < K; k0 += 32) {
    bf16x8 a[4], b[4];
#pragma unroll
    for (int mt = 0; mt < 4; mt++) {
      int rb = rowbase + mt * 16 + r;
      if (rb >= M) rb = 0;
      a[mt] = *(const bf16x8*)(A + (size_t)rb * K + k0 + q * 8);
    }
#pragma unroll
    for (int nt = 0; nt < 4; nt++)
      b[nt] = *(const bf16x8*)(Bm + (size_t)(colbase + nt * 16 + r) * K + k0 + q * 8);
#pragma unroll
    for (int mt = 0; mt < 4; mt++)
#pragma unroll
      for (int nt = 0; nt < 4; nt++)
        acc[mt][nt] = MFMA16(a[mt], b[nt], acc[mt][nt], 0, 0, 0);
  }
#pragma unroll
  for (int nt = 0; nt < 4; nt++) {
    int gn = colbase + nt * 16 + r;
    float bb = b0[gn] + b1[gn];
#pragma unroll
    for (int mt = 0; mt < 4; mt++)
#pragma unroll
      for (int j = 0; j < 4; j++) {
        int gm = rowbase + mt * 16 + q * 4 + j;
        if (gm < M) C[(size_t)gm * N + gn] = acc[mt][nt][j] + bb;
      }
  }
}

// ---------------- persistent recurrence kernel ----------------
// 64 blocks x 256 thr (4 waves = 4 gates). LDS: weights swizzled, gate-exchange buffer.
// enc: Wsh[64][512]@0 (64KB), hsh[32][512]@65536 (32KB), gates@98304 (8.7KB)
// dec: Wsh[64][1024]@0 (128KB), gates@131072 (8.7KB)
#define ENC_H_OFF 65536
#define ENC_G_OFF 98304
#define DEC_G_OFF 131072
__global__ __launch_bounds__(256, 1) void recurrence_kernel(
    const u16* __restrict__ Wbf_e,   // [4096][512]  (fwd 0..2047, rev 2048..)
    const u16* __restrict__ Wbf_d,   // [4096][1024]
    const float* __restrict__ Aef, const float* __restrict__ Aer, const float* __restrict__ Ad,
    const int* __restrict__ src_lens,
    float* __restrict__ ss, float* __restrict__ hs_dec, u16* __restrict__ Ybf,
    u16* __restrict__ hbf_e,   // [2 parity][2 lstm][32][512]
    u16* __restrict__ hbf_d,   // [2 parity][32][1024]
    unsigned* bar) {
  __shared__ __align__(16) char smem[139776];
  const int tid = threadIdx.x;
  const int bid = blockIdx.x;
  const int wave = tid >> 6, lane = tid & 63;
  const int r = lane & 15, q = lane >> 4;
  const int g = wave;
  const int ob = tid >> 3;            // epilogue: output batch
  const int oj = (tid & 7) * 2;       // epilogue: output col pair within 16

  // ================= encoder =================
  {
    const int lstm = bid >> 5, jt = bid & 31;
    float* gates = (float*)(smem + ENC_G_OFF);
    // stage W slice once: 64 rows (4 gates x 16 jcols) x 512, swizzled
    for (int c = tid; c < 64 * 64; c += 256) {
      int lr = c >> 6, c8 = (c & 63) * 8;
      int grow = lstm * 2048 + (lr >> 4) * 512 + jt * 16 + (lr & 15);
      uint4 v = *(const uint4*)(Wbf_e + (size_t)grow * 512 + c8);
      *(uint4*)(smem + ((lr * 1024 + c8 * 2) ^ ((lr & 7) << 4))) = v;
    }
    float creg0 = 0.f, creg1 = 0.f;
    const int jcol = jt * 16 + oj;
    for (int t = 0; t < NS; t++) {
      // stage h (zeros at t=0), swizzled
      const u16* hsrc = hbf_e + ((size_t)(t & 1) * 2 + lstm) * 16384;
      for (int c = tid; c < 32 * 64; c += 256) {
        int hr = c >> 6, c8 = (c & 63) * 8;
        int baddr = ENC_H_OFF + ((hr * 1024 + c8 * 2) ^ ((hr & 7) << 4));
        if (t == 0) {
          uint4 z = {0u, 0u, 0u, 0u};
          *(uint4*)(smem + baddr) = z;
        } else {
          *(uint4*)(smem + baddr) = *(const uint4*)(hsrc + (size_t)hr * 512 + c8);
        }
      }
      __syncthreads();
      f32x4 acc0 = {0.f,0.f,0.f,0.f}, acc1 = {0.f,0.f,0.f,0.f};
      for (int ks = 0; ks < 512; ks += 32) {
        int col2 = (ks + q * 8) * 2;
        int a0r = r, a1r = 16 + r, br = g * 16 + r;
        bf16x8 a0 = *(const bf16x8*)(smem + (ENC_H_OFF + ((a0r * 1024 + col2) ^ ((a0r & 7) << 4))));
        bf16x8 a1 = *(const bf16x8*)(smem + (ENC_H_OFF + ((a1r * 1024 + col2) ^ ((a1r & 7) << 4))));
        bf16x8 bf = *(const bf16x8*)(smem + ((br * 1024 + col2) ^ ((br & 7) << 4)));
        acc0 = MFMA16(a0, bf, acc0, 0, 0, 0);
        acc1 = MFMA16(a1, bf, acc1, 0, 0, 0);
      }
#pragma unroll
      for (int j = 0; j < 4; j++) {
        gates[(g * 32 + q * 4 + j) * 17 + r] = acc0[j];
        gates[(g * 32 + 16 + q * 4 + j) * 17 + r] = acc1[j];
      }
      __syncthreads();
      // epilogue: 2 outputs per thread
      {
        const float* Ae = lstm ? Aer : Aef;
        size_t abase = ((size_t)ob * NS + t) * 2048;
        float2 vi = *(const float2*)(Ae + abase + jcol);
        float2 vf = *(const float2*)(Ae + abase + 512 + jcol);
        float2 vg = *(const float2*)(Ae + abase + 1024 + jcol);
        float2 vo = *(const float2*)(Ae + abase + 1536 + jcol);
        float I0 = vi.x + gates[(0 * 32 + ob) * 17 + oj];
        float I1 = vi.y + gates[(0 * 32 + ob) * 17 + oj + 1];
        float F0 = vf.x + gates[(1 * 32 + ob) * 17 + oj];
        float F1 = vf.y + gates[(1 * 32 + ob) * 17 + oj + 1];
        float G0 = vg.x + gates[(2 * 32 + ob) * 17 + oj];
        float G1 = vg.y + gates[(2 * 32 + ob) * 17 + oj + 1];
        float O0 = vo.x + gates[(3 * 32 + ob) * 17 + oj];
        float O1 = vo.y + gates[(3 * 32 + ob) * 17 + oj + 1];
        float c0 = sigmf(F0) * creg0 + sigmf(I0) * tanhf(G0);
        float c1 = sigmf(F1) * creg1 + sigmf(I1) * tanhf(G1);
        float h0 = sigmf(O0) * tanhf(c0);
        float h1 = sigmf(O1) * tanhf(c1);
        creg0 = c0; creg1 = c1;
        ushort2 hw; hw.x = f2bf(h0); hw.y = f2bf(h1);
        *(ushort2*)(hbf_e + ((size_t)((t + 1) & 1) * 2 + lstm) * 16384 + ob * 512 + jcol) = hw;
        float2 hv; hv.x = h0; hv.y = h1;
        *(float2*)(ss + ((size_t)ob * NS + t) * NHD + lstm * 512 + jcol) = hv;
      }
      gridbar(bar, RECB);
    }
  }

  // ================= decoder init + W stage =================
  if (bid < 32) {
    int b = bid, s = src_lens[b] - 1;
    for (int j = tid; j < NHD; j += 256)
      hbf_d[b * NHD + j] = f2bf(ss[((size_t)b * NS + s) * NHD + j]);
  }
  {
    // stage dec W slice: 64 rows x 1024, swizzled (overwrites enc LDS; enc fully done)
    const int jt = bid;
    for (int c = tid; c < 64 * 128; c += 256) {
      int lr = c >> 7, c8 = (c & 127) * 8;
      int grow = (lr >> 4) * 1024 + jt * 16 + (lr & 15);
      uint4 v = *(const uint4*)(Wbf_d + (size_t)grow * 1024 + c8);
      *(uint4*)(smem + ((lr * 2048 + c8 * 2) ^ ((lr & 7) << 4))) = v;
    }
  }
  gridbar(bar, RECB);

  // ================= decoder =================
  {
    const int jt = bid;
    const int jcol = jt * 16 + oj;
    float* gates = (float*)(smem + DEC_G_OFF);
    float cd0 = 0.f, cd1 = 0.f;
    for (int t = 0; t < NT - 1; t++) {
      const u16* hcur = hbf_d + (size_t)(t & 1) * (32 * NHD);
      f32x4 acc0 = {0.f,0.f,0.f,0.f}, acc1 = {0.f,0.f,0.f,0.f};
      for (int ks = 0; ks < NHD; ks += 32) {
        int ko = ks + q * 8;
        bf16x8 a0 = *(const bf16x8*)(hcur + (size_t)r * NHD + ko);
        bf16x8 a1 = *(const bf16x8*)(hcur + (size_t)(16 + r) * NHD + ko);
        int br = g * 16 + r;
        bf16x8 bf = *(const bf16x8*)(smem + ((br * 2048 + ko * 2) ^ ((br & 7) << 4)));
        acc0 = MFMA16(a0, bf, acc0, 0, 0, 0);
        acc1 = MFMA16(a1, bf, acc1, 0, 0, 0);
      }
#pragma unroll
      for (int j = 0; j < 4; j++) {
        gates[(g * 32 + q * 4 + j) * 17 + r] = acc0[j];
        gates[(g * 32 + 16 + q * 4 + j) * 17 + r] = acc1[j];
      }
      __syncthreads();
      {
        const float* ad = Ad + ((size_t)t * NB + ob) * 4096;
        float2 vi = *(const float2*)(ad + jcol);
        float2 vf = *(const float2*)(ad + 1024 + jcol);
        float2 vg = *(const float2*)(ad + 2048 + jcol);
        float2 vo = *(const float2*)(ad + 3072 + jcol);
        float I0 = vi.x + gates[(0 * 32 + ob) * 17 + oj];
        float I1 = vi.y + gates[(0 * 32 + ob) * 17 + oj + 1];
        float F0 = vf.x + gates[(1 * 32 + ob) * 17 + oj];
        float F1 = vf.y + gates[(1 * 32 + ob) * 17 + oj + 1];
        float G0 = vg.x + gates[(2 * 32 + ob) * 17 + oj];
        float G1 = vg.y + gates[(2 * 32 + ob) * 17 + oj + 1];
        float O0 = vo.x + gates[(3 * 32 + ob) * 17 + oj];
        float O1 = vo.y + gates[(3 * 32 + ob) * 17 + oj + 1];
        float c0 = sigmf(F0) * cd0 + sigmf(I0) * tanhf(G0);
        float c1 = sigmf(F1) * cd1 + sigmf(I1) * tanhf(G1);
        float h0 = sigmf(O0) * tanhf(c0);
        float h1 = sigmf(O1) * tanhf(c1);
        cd0 = c0; cd1 = c1;
        size_t rowY = (size_t)t * NB + ob;
        ushort2 hw; hw.x = f2bf(h0); hw.y = f2bf(h1);
        *(ushort2*)(hbf_d + (size_t)((t + 1) & 1) * (32 * NHD) + ob * NHD + jcol) = hw;
        *(ushort2*)(Ybf + rowY * 2048 + jcol) = hw;
        float2 hv; hv.x = h0; hv.y = h1;
        *(float2*)(hs_dec + rowY * NHD + jcol) = hv;
      }
      if (t != NT - 2) gridbar(bar, RECB);
    }
  }
}

// ---------------- batched attention: block per (t,b) row, ctx -> Ybf[:,1024:2048] ----------------
__global__ __launch_bounds__(256) void attn_kernel(const float* __restrict__ hs,
                                                   const float* __restrict__ ss,
                                                   const int* __restrict__ src_lens,
                                                   u16* __restrict__ Ybf) {
  __shared__ __align__(16) float hsh[NHD];
  __shared__ float sc[NS];
  __shared__ float att[NS];
  int rr = blockIdx.x;
  int b = rr & 31;
  int tid = threadIdx.x;
  for (int i = tid; i < NHD; i += 256) hsh[i] = hs[(size_t)rr * NHD + i];
  __syncthreads();
  {
    int s = tid >> 2, q = tid & 3;
    const float4* row = (const float4*)(ss + ((size_t)b * NS + s) * NHD);
    const float4* h4 = (const float4*)hsh;
    float p = 0.f;
    for (int k = q * 64; k < q * 64 + 64; k++) {
      float4 hh = h4[k];
      float4 r4 = row[k];
      p += hh.x * r4.x + hh.y * r4.y + hh.z * r4.z + hh.w * r4.w;
    }
    p += __shfl_xor(p, 1);
    p += __shfl_xor(p, 2);
    if (q == 0) sc[s] = (s < src_lens[b]) ? p : -1e9f;
  }
  __syncthreads();
  if (tid < 64) {
    float v = sc[tid];
    float m = v;
#pragma unroll
    for (int off = 1; off < 64; off <<= 1) m = fmaxf(m, __shfl_xor(m, off));
    float e = expf(v - m);
    float ssum = e;
#pragma unroll
    for (int off = 1; off < 64; off <<= 1) ssum += __shfl_xor(ssum, off);
    att[tid] = e / ssum;
  }
  __syncthreads();
  float a0 = 0, a1 = 0, a2 = 0, a3 = 0;
  int d = tid * 4;
  for (int s2 = 0; s2 < NS; s2++) {
    float a = att[s2];
    const float4 r4 = *(const float4*)(ss + ((size_t)b * NS + s2) * NHD + d);
    a0 += a * r4.x; a1 += a * r4.y; a2 += a * r4.z; a3 += a * r4.w;
  }
  ushort4 o;
  o.x = f2bf(a0); o.y = f2bf(a1); o.z = f2bf(a2); o.w = f2bf(a3);
  *(ushort4*)(Ybf + (size_t)rr * 2048 + NHD + d) = o;
}

// ---------------- MFMA logits GEMM + in-register chunked logsumexp ----------------
// grid (16 row-tiles, 250 col-tiles), 256 thr (2x2 waves of 64x64).
__global__ __launch_bounds__(256) void gemmlse_mfma(
    const u16* __restrict__ Y,   // [2016][2048] bf16 (rows padded-clamped)
    const u16* __restrict__ Wo,  // [32000][2048] bf16
    const float* __restrict__ bo, const int* __restrict__ trg_tok,
    float* __restrict__ pm, float* __restrict__ ps, float* __restrict__ tgtlog) {
  __shared__ int tgtc[128];
  __shared__ float pmp[2][128];
  __shared__ float psp[2][128];
  int tid = threadIdx.x;
  int wave = tid >> 6, lane = tid & 63;
  int r = lane & 15, q = lane >> 4;
  int mh = wave >> 1, nh = wave & 1;
  int bm = blockIdx.x, bn = blockIdx.y;
  if (tid < 128) {
    int gm = bm * 128 + tid;
    int tt = gm >> 5, b = gm & 31;
    tgtc[tid] = (gm < NR) ? trg_tok[b * NT + tt + 1] : -1;
  }
  __syncthreads();
  int rowbase = bm * 128 + mh * 64;
  int colbase = bn * 128 + nh * 64;
  f32x4 acc[4][4] = {};
  for (int k0 = 0; k0 < 2048; k0 += 32) {
    bf16x8 a[4], b[4];
#pragma unroll
    for (int mt = 0; mt < 4; mt++) {
      int rb = rowbase + mt * 16 + r;
      if (rb >= NR) rb = 0;
      a[mt] = *(const bf16x8*)(Y + (size_t)rb * 2048 + k0 + q * 8);
    }
#pragma unroll
    for (int nt = 0; nt < 4; nt++)
      b[nt] = *(const bf16x8*)(Wo + (size_t)(colbase + nt * 16 + r) * 2048 + k0 + q * 8);
#pragma unroll
    for (int mt = 0; mt < 4; mt++)
#pragma unroll
      for (int nt = 0; nt < 4; nt++)
        acc[mt][nt] = MFMA16(a[mt], b[nt], acc[mt][nt], 0, 0, 0);
  }
  // bias
  float bo4[4];
#pragma unroll
  for (int nt = 0; nt < 4; nt++) bo4[nt] = bo[colbase + nt * 16 + r];
#pragma unroll
  for (int mt = 0; mt < 4; mt++)
#pragma unroll
    for (int nt = 0; nt < 4; nt++)
#pragma unroll
      for (int j = 0; j < 4; j++) acc[mt][nt][j] += bo4[nt];
  // in-register row-wise lse over this wave's 64 cols + target capture
#pragma unroll
  for (int mt = 0; mt < 4; mt++) {
#pragma unroll
    for (int j = 0; j < 4; j++) {
      float m = fmaxf(fmaxf(acc[mt][0][j], acc[mt][1][j]), fmaxf(acc[mt][2][j], acc[mt][3][j]));
      m = fmaxf(m, __shfl_xor(m, 1));
      m = fmaxf(m, __shfl_xor(m, 2));
      m = fmaxf(m, __shfl_xor(m, 4));
      m = fmaxf(m, __shfl_xor(m, 8));
      float s = expf(acc[mt][0][j] - m) + expf(acc[mt][1][j] - m) +
                expf(acc[mt][2][j] - m) + expf(acc[mt][3][j] - m);
      s += __shfl_xor(s, 1);
      s += __shfl_xor(s, 2);
      s += __shfl_xor(s, 4);
      s += __shfl_xor(s, 8);
      int lrow = mh * 64 + mt * 16 + q * 4 + j;
      if (r == 0) { pmp[nh][lrow] = m; psp[nh][lrow] = s; }
      int tc = tgtc[lrow];
      int off = tc - (bn * 128 + nh * 64);
      if (off >= 0 && off < 64 && (off & 15) == r) {
        tgtlog[bm * 128 + lrow] = acc[mt][off >> 4][j];
      }
    }
  }
  __syncthreads();
  if (tid < 128) {
    int gm = bm * 128 + tid;
    if (gm < NR) {
      float m0 = pmp[0][tid], m1 = pmp[1][tid];
      float m = fmaxf(m0, m1);
      float s = psp[0][tid] * expf(m0 - m) + psp[1][tid] * expf(m1 - m);
      pm[(size_t)bn * NR + gm] = m;
      ps[(size_t)bn * NR + gm] = s;
    }
  }
}

// ---------------- merge per-chunk lse partials, apply mask ----------------
__global__ void lse_combine_kernel(const float* __restrict__ pm, const float* __restrict__ ps,
                                   const float* __restrict__ tgtlog, const int* __restrict__ trg_lens,
                                   float* __restrict__ rowval) {
  int rr = blockIdx.x * blockDim.x + threadIdx.x;
  if (rr >= NR) return;
  float m = -1e30f;
  for (int i = 0; i < NCT; i++) m = fmaxf(m, pm[(size_t)i * NR + rr]);
  float s = 0.f;
  for (int i = 0; i < NCT; i++) s += ps[(size_t)i * NR + rr] * expf(pm[(size_t)i * NR + rr] - m);
  float lse = m + logf(s);
  int t = rr >> 5, b = rr & 31;
  float v = tgtlog[rr] - lse;
  rowval[rr] = ((t + 1) < trg_lens[b]) ? v : 0.f;
}

__global__ void final_reduce_kernel(const float* __restrict__ rowval, float* __restrict__ out) {
  __shared__ float sm[256];
  float s = 0.f;
  for (int i = threadIdx.x; i < NR; i += 256) s += rowval[i];
  sm[threadIdx.x] = s;
  __syncthreads();
  for (int off = 128; off > 0; off >>= 1) {
    if (threadIdx.x < off) sm[threadIdx.x] += sm[threadIdx.x + off];
    __syncthreads();
  }
  if (threadIdx.x == 0) out[0] = sm[0];
}

extern "C" void kernel_launch(void* const* d_in, const int* in_sizes, int n_in,
                              void* d_out, int out_size, void* d_ws, size_t ws_size,
                              hipStream_t stream) {
  const int* src_tokens = (const int*)d_in[0];
  const int* src_lens = (const int*)d_in[1];
  const int* trg_tokens = (const int*)d_in[2];
  const int* trg_lens = (const int*)d_in[3];
  const float* src_emb = (const float*)d_in[4];
  const float* trg_emb = (const float*)d_in[5];
  const float* We_ih = (const float*)d_in[6];
  const float* We_hh = (const float*)d_in[7];
  const float* be_ih = (const float*)d_in[8];
  const float* be_hh = (const float*)d_in[9];
  const float* Wr_ih = (const float*)d_in[10];
  const float* Wr_hh = (const float*)d_in[11];
  const float* br_ih = (const float*)d_in[12];
  const float* br_hh = (const float*)d_in[13];
  const float* Wd_ih = (const float*)d_in[14];
  const float* Wd_hh = (const float*)d_in[15];
  const float* bd_ih = (const float*)d_in[16];
  const float* bd_hh = (const float*)d_in[17];
  const float* W_out = (const float*)d_in[18];
  const float* b_out = (const float*)d_in[19];

  char* base = (char*)d_ws;
  size_t off = 0;
  auto alloc = [&](size_t bytes) -> char* {
    char* p = base + off;
    off += (bytes + 255) & ~(size_t)255;
    return p;
  };
  u16* xsrcb = (u16*)alloc((size_t)2048 * 512 * 2);
  u16* xtrgb = (u16*)alloc((size_t)NR * 512 * 2);
  u16* Wihe = (u16*)alloc((size_t)2048 * 512 * 2);
  u16* Wihr = (u16*)alloc((size_t)2048 * 512 * 2);
  u16* Wihd = (u16*)alloc((size_t)4096 * 512 * 2);
  u16* Wbf_e = (u16*)alloc((size_t)4096 * 512 * 2);
  u16* Wbf_d = (u16*)alloc((size_t)4096 * 1024 * 2);
  u16* Wobf = (u16*)alloc((size_t)NV * 2048 * 2);
  float* Aef = (float*)alloc((size_t)2048 * 2048 * 4);
  float* Aer = (float*)alloc((size_t)2048 * 2048 * 4);
  float* Ad  = (float*)alloc((size_t)NR * 4096 * 4);
  float* ss  = (float*)alloc((size_t)NB * NS * NHD * 4);
  float* hs_dec = (float*)alloc((size_t)NR * NHD * 4);
  u16* Ybf = (u16*)alloc((size_t)NR * 2048 * 2);
  u16* hbf_e = (u16*)alloc((size_t)4 * 32 * 512 * 2);
  u16* hbf_d = (u16*)alloc((size_t)2 * 32 * NHD * 2);
  float* pm = (float*)alloc((size_t)NCT * NR * 4);
  float* ps = (float*)alloc((size_t)NCT * NR * 4);
  float* tgtlog = (float*)alloc((size_t)NR * 4);
  float* rowval = (float*)alloc((size_t)NR * 4);
  unsigned* bar = (unsigned*)alloc(256);

  init_bar_kernel<<<1, 64, 0, stream>>>(bar);

  // gathers (bf16 out)
  gather_src_bf16<<<512, 256, 0, stream>>>(src_tokens, src_emb, xsrcb);
  gather_trg_bf16<<<(NR * 64 + 255) / 256, 256, 0, stream>>>(trg_tokens, trg_emb, xtrgb);

  // weight conversions
  cvt_bf16_kernel<<<512, 256, 0, stream>>>(We_ih, Wihe, (long)2048 * 512);
  cvt_bf16_kernel<<<512, 256, 0, stream>>>(Wr_ih, Wihr, (long)2048 * 512);
  cvt_bf16_kernel<<<1024, 256, 0, stream>>>(Wd_ih, Wihd, (long)4096 * 512);
  cvt_bf16_kernel<<<512, 256, 0, stream>>>(We_hh, Wbf_e, (long)2048 * 512);
  cvt_bf16_kernel<<<512, 256, 0, stream>>>(Wr_hh, Wbf_e + (size_t)2048 * 512, (long)2048 * 512);
  cvt_bf16_kernel<<<2048, 256, 0, stream>>>(Wd_hh, Wbf_d, (long)4096 * 1024);
  cvt_bf16_kernel<<<32000, 256, 0, stream>>>(W_out, Wobf, (long)NV * 2048);

  // input-gate GEMMs (bf16 MFMA, both biases folded)
  mfma_gemm_bias<<<dim3(16, 16), 256, 0, stream>>>(xsrcb, Wihe, be_ih, be_hh, Aef, 2048, 2048, 512);
  mfma_gemm_bias<<<dim3(16, 16), 256, 0, stream>>>(xsrcb, Wihr, br_ih, br_hh, Aer, 2048, 2048, 512);
  mfma_gemm_bias<<<dim3(16, 32), 256, 0, stream>>>(xtrgb, Wihd, bd_ih, bd_hh, Ad, NR, 4096, 512);

  // full recurrence: encoder + decoder in one persistent kernel
  recurrence_kernel<<<RECB, 256, 0, stream>>>(Wbf_e, Wbf_d, Aef, Aer, Ad, src_lens,
                                              ss, hs_dec, Ybf, hbf_e, hbf_d, bar);

  // batched attention (ctx only feeds logits)
  attn_kernel<<<NR, 256, 0, stream>>>(hs_dec, ss, src_lens, Ybf);

  // fused bf16-MFMA logits GEMM + chunked logsumexp
  gemmlse_mfma<<<dim3(16, NCT), 256, 0, stream>>>(Ybf, Wobf, b_out, trg_tokens, pm, ps, tgtlog);
  lse_combine_kernel<<<(NR + 255) / 256, 256, 0, stream>>>(pm, ps, tgtlog, trg_lens, rowval);
  final_reduce_kernel<<<1, 256, 0, stream>>>(rowval, (float*)d_out);
}